// Round 9
// baseline (343.014 us; speedup 1.0000x reference)
//
#include <hip/hip_runtime.h>
#include <stdint.h>

typedef unsigned short u16;
typedef unsigned int u32;
typedef __attribute__((ext_vector_type(8))) __bf16 bf16x8;
typedef __attribute__((ext_vector_type(4))) float f32x4;

#define M_TOT 16384   // B*N tokens
#define DIMX  1024

// RNE float->bf16 (finite inputs only)
__device__ __forceinline__ u16 f2b(float f) {
  u32 u = __builtin_bit_cast(u32, f);
  u32 r = (u + 0x7fffu + ((u >> 16) & 1u)) >> 16;
  return (u16)r;
}

__device__ __forceinline__ void gl2lds16(const void* g, void* l) {
  __builtin_amdgcn_global_load_lds((const __attribute__((address_space(1))) void*)g,
                                   (__attribute__((address_space(3))) void*)l,
                                   16, 0, 0);
}

// ---------------- RMSNorm ----------------
__global__ __launch_bounds__(256) void k_rms(const float* __restrict__ x,
                                             const float* __restrict__ gamma,
                                             u16* __restrict__ xn) {
  int row = blockIdx.x;
  int t = threadIdx.x;
  const float4* xr = (const float4*)(x + (size_t)row * DIMX);
  float4 v = xr[t];
  float ss = v.x * v.x + v.y * v.y + v.z * v.z + v.w * v.w;
#pragma unroll
  for (int o = 32; o > 0; o >>= 1) ss += __shfl_xor(ss, o, 64);
  __shared__ float wss[4];
  int w = t >> 6;
  if ((t & 63) == 0) wss[w] = ss;
  __syncthreads();
  float tot = wss[0] + wss[1] + wss[2] + wss[3];
  float scale = 32.0f / fmaxf(sqrtf(tot), 1e-12f);
  float4 g = ((const float4*)gamma)[t];
  ushort4 o4;
  o4.x = f2b(v.x * scale * g.x);
  o4.y = f2b(v.y * scale * g.y);
  o4.z = f2b(v.z * scale * g.z);
  o4.w = f2b(v.w * scale * g.w);
  ((ushort4*)xn)[(size_t)row * 256 + t] = o4;
}

// ---- weights: wqT = (wqkv[:, :2048])^T, woT = wout^T, wvc = cast(wqkv[:, 2048:]) ----
__global__ __launch_bounds__(256) void k_castT2(const float* __restrict__ wqkv,
                                                const float* __restrict__ wout,
                                                u16* __restrict__ wqT,
                                                u16* __restrict__ woT,
                                                u16* __restrict__ wvc) {
  __shared__ float tile[32][33];
  int bx = blockIdx.x;
  int r0 = blockIdx.y * 32;
  int tx = threadIdx.x, ty = threadIdx.y;
  if (bx < 96) {
    const float* in; u16* out; int Cc; int c0;
    if (bx < 64) { in = wqkv; out = wqT; Cc = 3072; c0 = bx * 32; }
    else         { in = wout; out = woT; Cc = 1024; c0 = (bx - 64) * 32; }
#pragma unroll
    for (int i = 0; i < 4; i++)
      tile[ty + i * 8][tx] = in[(size_t)(r0 + ty + i * 8) * Cc + c0 + tx];
    __syncthreads();
#pragma unroll
    for (int i = 0; i < 4; i++)
      out[(size_t)(c0 + ty + i * 8) * 1024 + r0 + tx] = f2b(tile[tx][ty + i * 8]);
  } else {
    int c0 = (bx - 96) * 32;
#pragma unroll
    for (int i = 0; i < 4; i++) {
      int r = r0 + ty + i * 8;
      wvc[(size_t)r * 1024 + c0 + tx] = f2b(wqkv[(size_t)r * 3072 + 2048 + c0 + tx]);
    }
  }
}

// ---------------- xn (b: 4096 x 1024) -> xnT (b: 1024 x 4096) bf16 ----------------
__global__ __launch_bounds__(256) void k_xT(const u16* __restrict__ xn,
                                            u16* __restrict__ xnT) {
  __shared__ u16 tile[64][65];
  int bz = blockIdx.z;
  int n0 = blockIdx.x * 64, c0 = blockIdx.y * 64;
  int tx = threadIdx.x, ty = threadIdx.y;   // (64,4)
  const u16* in = xn + (size_t)bz * 4096 * 1024;
  u16* out = xnT + (size_t)bz * 1024 * 4096;
#pragma unroll
  for (int i = 0; i < 16; i++)
    tile[ty + i * 4][tx] = in[(size_t)(n0 + ty + i * 4) * 1024 + c0 + tx];
  __syncthreads();
#pragma unroll
  for (int i = 0; i < 16; i++)
    out[(size_t)(c0 + ty + i * 4) * 4096 + n0 + tx] = tile[tx][ty + i * 4];
}

// ---------------- 256x128 8-wave GEMM core, BK=32, dbuf, swizzled (R8, verified) ----
// Generalized: runtime row strides ldA/ldB and step count (K = 32*nsteps).
// Slot s of row holds global k-chunk s ^ ((row>>1)&3) (pre-swizzled SOURCE,
// linear LDS dest); reads fetch chunk q from slot q ^ ((row>>1)&3) -> 2-way = free.

template<bool SWAP>
__device__ __forceinline__ f32x4 mf(bf16x8 a, bf16x8 b, f32x4 c) {
  return SWAP ? __builtin_amdgcn_mfma_f32_16x16x32_bf16(b, a, c, 0, 0, 0)
              : __builtin_amdgcn_mfma_f32_16x16x32_bf16(a, b, c, 0, 0, 0);
}

__device__ __forceinline__ void stage_ab(const u16* __restrict__ Ag,
                                         const u16* __restrict__ Bg,
                                         u16* dstA, u16* dstB, int t, int k0,
                                         int ldA, int ldB) {
#pragma unroll
  for (int r = 0; r < 2; r++) {
    int c = r * 512 + t;
    int row = c >> 2, s = c & 3;
    int g = s ^ ((row >> 1) & 3);                // inverse swizzle on source
    gl2lds16(Ag + (size_t)row * ldA + k0 + g * 8,
             dstA + (r * 512 + (t >> 6) * 64) * 8);   // wave-uniform base
  }
  {
    int row = t >> 2, s = t & 3;
    int g = s ^ ((row >> 1) & 3);
    gl2lds16(Bg + (size_t)row * ldB + k0 + g * 8,
             dstB + ((t >> 6) * 64) * 8);
  }
}

template<bool SWAP>
__device__ __forceinline__ void gemm_core(const u16* __restrict__ Ag,
                                          const u16* __restrict__ Bg,
                                          u16* lds, int t, f32x4 (&acc)[4][4],
                                          int ldA, int ldB, int nsteps) {
  const int lane = t & 63;
  const int r16 = lane & 15, q = lane >> 4;
  const int wr = (t >> 6) >> 1, wc = (t >> 6) & 1;
  const int arow = wr * 64 + r16;
  const int brow = wc * 64 + r16;

  stage_ab(Ag, Bg, lds, lds + 8192, t, 0, ldA, ldB);
  asm volatile("s_waitcnt vmcnt(0)" ::: "memory");
  __builtin_amdgcn_s_barrier();

  bf16x8 af[4], bf[4];
#pragma unroll 1
  for (int tt = 0; tt < nsteps; tt++) {
    const int cur = (tt & 1) ? 12288 : 0;
    const int nxt = cur ^ 12288;
    int k1 = (tt + 1 == nsteps) ? 0 : (tt + 1) * 32;  // wrap: harmless re-stage
    stage_ab(Ag, Bg, lds + nxt, lds + nxt + 8192, t, k1, ldA, ldB);
    const u16* A = lds + cur;
    const u16* B = lds + cur + 8192;
#pragma unroll
    for (int i = 0; i < 4; i++) {
      int ar = i * 16 + arow;
      int br = i * 16 + brow;
      af[i] = *(const bf16x8*)(A + ar * 32 + (q ^ ((ar >> 1) & 3)) * 8);
      bf[i] = *(const bf16x8*)(B + br * 32 + (q ^ ((br >> 1) & 3)) * 8);
    }
    __builtin_amdgcn_s_setprio(1);
#pragma unroll
    for (int i = 0; i < 4; i++)
#pragma unroll
      for (int j = 0; j < 4; j++)
        acc[i][j] = mf<SWAP>(af[i], bf[j], acc[i][j]);
    __builtin_amdgcn_s_setprio(0);
    asm volatile("s_waitcnt vmcnt(0)" ::: "memory");
    __builtin_amdgcn_s_barrier();
  }
}

// ---------------- G partials: Gp[s][b] = xnT_b[:, s*1024:+1024] x itself^T ----------
__global__ __launch_bounds__(512, 4) void k_G(const u16* __restrict__ xnT,
                                              float* __restrict__ Gp) {
  __shared__ u16 lds[2 * 12288];
  int l = blockIdx.x;
  int s = l & 3, b = (l >> 2) & 3;
  int tile = l >> 4;                   // 0..31
  int mt = tile >> 3, nt = tile & 7;
  int m0 = mt * 256, n0 = nt * 128;
  const u16* base = xnT + (size_t)b * 1024 * 4096 + s * 1024;
  int t = threadIdx.x, lane = t & 63;
  int r16 = lane & 15, q = lane >> 4;
  int wr = (t >> 6) >> 1, wc = (t >> 6) & 1;
  f32x4 acc[4][4] = {};
  gemm_core<true>(base + (size_t)m0 * 4096, base + (size_t)n0 * 4096,
                  lds, t, acc, 4096, 4096, 32);
  float* C = Gp + (size_t)(s * 4 + b) * 1048576;
#pragma unroll
  for (int i = 0; i < 4; i++) {
    int m = m0 + wr * 64 + i * 16 + r16;
#pragma unroll
    for (int j = 0; j < 4; j++) {
      int cc = n0 + wc * 64 + j * 16 + q * 4;
      *(f32x4*)(C + (size_t)m * 1024 + cc) = acc[i][j];
    }
  }
}

// ---------------- G = sum_s Gp (bf16) ----------------
__global__ __launch_bounds__(256) void k_Gred(const float* __restrict__ Gp,
                                              u16* __restrict__ G) {
  size_t i = ((size_t)blockIdx.x * 256 + threadIdx.x) * 4;   // over 4M f32
  f32x4 v = {};
#pragma unroll
  for (int s = 0; s < 4; s++)
    v += *(const f32x4*)(Gp + (size_t)s * 4194304 + i);
  ushort4 o4;
  o4.x = f2b(v.x); o4.y = f2b(v.y); o4.z = f2b(v.z); o4.w = f2b(v.w);
  *(ushort4*)(G + i) = o4;
}

// ---------------- V = [WqT; WkT] (2048x1024) x G_b (symmetric) ----------------
__global__ __launch_bounds__(512, 4) void k_V(const u16* __restrict__ wqT,
                                              const u16* __restrict__ G,
                                              u16* __restrict__ V) {
  __shared__ u16 lds[2 * 12288];
  int l = blockIdx.x;
  int b = l & 3;
  int tile = l >> 2;                   // 0..63
  int mt = tile >> 3, nt = tile & 7;   // m: 2048/256, n: 1024/128
  int m0 = mt * 256, n0 = nt * 128;
  int t = threadIdx.x, lane = t & 63;
  int r16 = lane & 15, q = lane >> 4;
  int wr = (t >> 6) >> 1, wc = (t >> 6) & 1;
  f32x4 acc[4][4] = {};
  gemm_core<true>(wqT + (size_t)m0 * 1024,
                  G + (size_t)b * 1048576 + (size_t)n0 * 1024,
                  lds, t, acc, 1024, 1024, 32);
  u16* out = V + (size_t)b * 2097152;
#pragma unroll
  for (int i = 0; i < 4; i++) {
    int m = m0 + wr * 64 + i * 16 + r16;
#pragma unroll
    for (int j = 0; j < 4; j++) {
      int cc = n0 + wc * 64 + j * 16 + q * 4;
      f32x4 a = acc[i][j];
      ushort4 o4;
      o4.x = f2b(a.x); o4.y = f2b(a.y); o4.z = f2b(a.z); o4.w = f2b(a.w);
      *(ushort4*)(out + (size_t)m * 1024 + cc) = o4;
    }
  }
}

// ---------------- S_h[d][e] = sum_c V2[hd][c]*WkT[he][c]; norms = diag quad forms ----
__global__ __launch_bounds__(256) void k_S(const u16* __restrict__ V,
                                           const u16* __restrict__ wqT,
                                           float* __restrict__ Sbuf,
                                           float* __restrict__ norms) {
  int bh = blockIdx.x;
  int b = bh >> 4, h = bh & 15;
  int t = threadIdx.x, lane = t & 63, w = t >> 6;
  int r16 = lane & 15, q = lane >> 4;
  const u16* Vb = V + (size_t)b * 2097152;
  const u16* v2 = Vb + (size_t)(h * 64) * 1024;            // q-part rows
  const u16* wk = wqT + (size_t)(1024 + h * 64) * 1024;    // k rows
  int drow = w * 16 + r16;
  f32x4 acc[4] = {};
#pragma unroll 4
  for (int kk = 0; kk < 1024; kk += 32) {
    bf16x8 aq = *(const bf16x8*)(v2 + (size_t)drow * 1024 + kk + q * 8);
#pragma unroll
    for (int j = 0; j < 4; j++) {
      bf16x8 bk = *(const bf16x8*)(wk + (size_t)(j * 16 + r16) * 1024 + kk + q * 8);
      acc[j] = __builtin_amdgcn_mfma_f32_16x16x32_bf16(bk, aq, acc[j], 0, 0, 0);
    }
  }
  // acc[j]: d = drow (col), e = j*16 + q*4 + reg (row)  [same as verified attn_s]
  float* Sp = Sbuf + (size_t)bh * 4096;
#pragma unroll
  for (int j = 0; j < 4; j++)
    *(f32x4*)(Sp + drow * 64 + j * 16 + q * 4) = acc[j];
  // norms: nq2[d] = V[hd]·wqT[hd], nk2[e] = V[1024+he]·wqT[1024+he]
  if (t < 128) {
    int row = (t < 64) ? (h * 64 + t) : (1024 + h * 64 + (t - 64));
    const u16* vr = Vb + (size_t)row * 1024;
    const u16* wr2 = wqT + (size_t)row * 1024;
    float s = 0.f;
#pragma unroll 4
    for (int c = 0; c < 1024; c += 8) {
      bf16x8 a = *(const bf16x8*)(vr + c);
      bf16x8 bb = *(const bf16x8*)(wr2 + c);
#pragma unroll
      for (int k = 0; k < 8; k++) s += (float)a[k] * (float)bb[k];
    }
    norms[b * 2048 + row] = s;
  }
}

// ---------------- scale + softmax -> PT[bh][e][d] bf16 ----------------
__global__ __launch_bounds__(256) void k_softmax(const float* __restrict__ Sbuf,
                                                 const float* __restrict__ norms,
                                                 const float* __restrict__ temp,
                                                 u16* __restrict__ PT) {
  int bh = blockIdx.x;
  int b = bh >> 4, h = bh & 15;
  int t = threadIdx.x;
  int d = t & 63, w = t >> 6;
  int e0 = w * 16;
  __shared__ float rnk[64];
  __shared__ float redm[4][64];
  __shared__ float reds[4][64];
  if (t < 64) rnk[t] = 1.0f / fmaxf(sqrtf(norms[b * 2048 + 1024 + h * 64 + t]), 1e-12f);
  __syncthreads();
  float nq = sqrtf(norms[b * 2048 + h * 64 + d]);
  float qs = 8.0f * __expf(temp[h]) / fmaxf(nq, 1e-12f);
  const float* Sp = Sbuf + (size_t)bh * 4096 + d * 64 + e0;
  float vals[16];
#pragma unroll
  for (int e = 0; e < 16; e += 4) {
    f32x4 v = *(const f32x4*)(Sp + e);
    vals[e + 0] = v.x; vals[e + 1] = v.y; vals[e + 2] = v.z; vals[e + 3] = v.w;
  }
  float mx = -3.0e38f;
#pragma unroll
  for (int e = 0; e < 16; e++) {
    float v = vals[e] * qs * rnk[e0 + e];
    vals[e] = v;
    mx = fmaxf(mx, v);
  }
  redm[w][d] = mx;
  __syncthreads();
  float M = fmaxf(fmaxf(redm[0][d], redm[1][d]), fmaxf(redm[2][d], redm[3][d]));
  float s = 0.f;
#pragma unroll
  for (int e = 0; e < 16; e++) {
    float v = __expf(vals[e] - M);
    vals[e] = v;
    s += v;
  }
  reds[w][d] = s;
  __syncthreads();
  float inv = 1.0f / (reds[0][d] + reds[1][d] + reds[2][d] + reds[3][d]);
#pragma unroll
  for (int e = 0; e < 16; e++)
    PT[((size_t)bh * 64 + e0 + e) * 64 + d] = f2b(vals[e] * inv);
}

// ---------------- MT_b[o][h*64+e] = sum_d woT[o][h*64+d] * PT[e][d] ----------------
__global__ __launch_bounds__(256) void k_m(const u16* __restrict__ woT,
                                           const u16* __restrict__ PT,
                                           u16* __restrict__ MT) {
  int bh = blockIdx.x;
  int b = bh >> 4, h = bh & 15;
  int o0 = blockIdx.y * 128;
  int t = threadIdx.x, lane = t & 63, w = t >> 6;
  int r16 = lane & 15, q = lane >> 4;
  const u16* pbase = PT + (size_t)bh * 4096;
  f32x4 acc[2][4] = {};
#pragma unroll
  for (int ks = 0; ks < 2; ks++) {
    int kk = ks * 32 + q * 8;
    bf16x8 af[2], bfr[4];
#pragma unroll
    for (int i = 0; i < 2; i++)
      af[i] = *(const bf16x8*)(woT + (size_t)(o0 + w * 32 + i * 16 + r16) * 1024 + h * 64 + kk);
#pragma unroll
    for (int j = 0; j < 4; j++)
      bfr[j] = *(const bf16x8*)(pbase + (size_t)(j * 16 + r16) * 64 + kk);
#pragma unroll
    for (int i = 0; i < 2; i++)
#pragma unroll
      for (int j = 0; j < 4; j++)
        acc[i][j] = __builtin_amdgcn_mfma_f32_16x16x32_bf16(af[i], bfr[j], acc[i][j], 0, 0, 0);
  }
  u16* dst = MT + (size_t)b * 1024 * 1024;
#pragma unroll
  for (int i = 0; i < 2; i++) {
    int o = o0 + w * 32 + i * 16 + q * 4;
#pragma unroll
    for (int j = 0; j < 4; j++) {
      int e = h * 64 + j * 16 + r16;
      f32x4 a = acc[i][j];
      dst[(size_t)(o + 0) * 1024 + e] = f2b(a.x);
      dst[(size_t)(o + 1) * 1024 + e] = f2b(a.y);
      dst[(size_t)(o + 2) * 1024 + e] = f2b(a.z);
      dst[(size_t)(o + 3) * 1024 + e] = f2b(a.w);
    }
  }
}

// ---------------- Mt_b[o][c] = sum_k wvc[c][k] * MT_b[o][k]  (M transposed) --------
__global__ __launch_bounds__(512, 4) void k_M2(const u16* __restrict__ wvc,
                                               const u16* __restrict__ MT,
                                               u16* __restrict__ Mt) {
  __shared__ u16 lds[2 * 12288];
  int l = blockIdx.x;
  int b = l & 3;
  int tile = l >> 2;                   // 0..31
  int mt = tile >> 3, nt = tile & 7;   // m: c-tiles 1024/256, n: o-tiles 1024/128
  int m0 = mt * 256, n0 = nt * 128;
  int t = threadIdx.x, lane = t & 63;
  int r16 = lane & 15, q = lane >> 4;
  int wr = (t >> 6) >> 1, wc = (t >> 6) & 1;
  f32x4 acc[4][4] = {};
  gemm_core<false>(wvc + (size_t)m0 * 1024,
                   MT + (size_t)b * 1048576 + (size_t)n0 * 1024,
                   lds, t, acc, 1024, 1024, 32);
  u16* out = Mt + (size_t)b * 1048576;
#pragma unroll
  for (int j = 0; j < 4; j++) {
    int cc = n0 + wc * 64 + j * 16 + r16;         // o (B-row)
#pragma unroll
    for (int i = 0; i < 4; i++) {
      int m = m0 + wr * 64 + i * 16 + q * 4;      // c (A-row, reg dim)
      f32x4 a = acc[i][j];
      ushort4 o4;
      o4.x = f2b(a.x); o4.y = f2b(a.y); o4.z = f2b(a.z); o4.w = f2b(a.w);
      *(ushort4*)(out + (size_t)cc * 1024 + m) = o4;
    }
  }
}

// ---------------- final: out = xn (16384x1024) x Mt_b^T (fp32) ----------------
__global__ __launch_bounds__(512, 4) void k_final(const u16* __restrict__ xn,
                                                  const u16* __restrict__ Mt,
                                                  float* __restrict__ C) {
  __shared__ u16 lds[2 * 12288];
  int l = blockIdx.x;
  int xcd = l & 7, c = l >> 3;        // c in [0,64)
  int mt = xcd * 8 + (c & 7);         // 0..63
  int nt = c >> 3;                    // 0..7
  int m0 = mt * 256, n0 = nt * 128;
  int b = m0 >> 12;
  int t = threadIdx.x, lane = t & 63;
  int r16 = lane & 15, q = lane >> 4;
  int wr = (t >> 6) >> 1, wc = (t >> 6) & 1;
  f32x4 acc[4][4] = {};
  gemm_core<true>(xn + (size_t)m0 * 1024,
                  Mt + (size_t)b * 1048576 + (size_t)n0 * 1024,
                  lds, t, acc, 1024, 1024, 32);
#pragma unroll
  for (int i = 0; i < 4; i++) {
    int m = m0 + wr * 64 + i * 16 + r16;
#pragma unroll
    for (int j = 0; j < 4; j++) {
      int cc = n0 + wc * 64 + j * 16 + q * 4;
      *(f32x4*)(C + (size_t)m * 1024 + cc) = acc[i][j];
    }
  }
}

extern "C" void kernel_launch(void* const* d_in, const int* in_sizes, int n_in,
                              void* d_out, int out_size, void* d_ws, size_t ws_size,
                              hipStream_t stream) {
  const float* x     = (const float*)d_in[0];
  const float* gamma = (const float*)d_in[1];
  const float* wqkv  = (const float*)d_in[2];
  const float* temp  = (const float*)d_in[3];
  const float* wout  = (const float*)d_in[4];
  float* out = (float*)d_out;

  char* ws = (char*)d_ws;
  u16* xn    = (u16*)(ws);                       // 33,554,432
  u16* xnT   = (u16*)(ws + 33554432);            // 33,554,432
  u16* wqT   = (u16*)(ws + 67108864);            //  4,194,304 (2048x1024)
  u16* woT   = (u16*)(ws + 71303168);            //  2,097,152
  u16* wvc   = (u16*)(ws + 73400320);            //  2,097,152
  u16* G     = (u16*)(ws + 75497472);            //  8,388,608
  float* norms = (float*)(ws + 83886080);        //     32,768
  char* R    = ws + 83918848;                    // 67,108,864 region, reused:
  float* Gp  = (float*)R;                        //   64 MB (dead after k_Gred)
  u16* V     = (u16*)R;                          //   16,777,216
  float* Sbuf = (float*)(R + 16777216);          //    1,048,576
  u16* PT    = (u16*)(R + 17825792);             //      524,288
  u16* MT    = (u16*)(R + 18350080);             //    8,388,608
  u16* Mt    = (u16*)(R + 26738688);             //    8,388,608

  k_rms<<<16384, 256, 0, stream>>>(x, gamma, xn);
  k_castT2<<<dim3(128, 32), dim3(32, 8), 0, stream>>>(wqkv, wout, wqT, woT, wvc);
  k_xT<<<dim3(64, 16, 4), dim3(64, 4), 0, stream>>>(xn, xnT);
  k_G<<<512, 512, 0, stream>>>(xnT, Gp);
  k_Gred<<<4096, 256, 0, stream>>>(Gp, G);
  k_V<<<256, 512, 0, stream>>>(wqT, G, V);
  k_S<<<64, 256, 0, stream>>>(V, wqT, Sbuf, norms);
  k_softmax<<<64, 256, 0, stream>>>(Sbuf, norms, temp, PT);
  k_m<<<dim3(64, 8), 256, 0, stream>>>(woT, PT, MT);
  k_M2<<<128, 512, 0, stream>>>(wvc, MT, Mt);
  k_final<<<512, 512, 0, stream>>>(xn, Mt, out);
}

// Round 10
// 331.547 us; speedup vs baseline: 1.0346x; 1.0346x over previous
//
#include <hip/hip_runtime.h>
#include <stdint.h>

typedef unsigned short u16;
typedef unsigned int u32;
typedef __attribute__((ext_vector_type(8))) __bf16 bf16x8;
typedef __attribute__((ext_vector_type(4))) float f32x4;

#define M_TOT 16384   // B*N tokens
#define DIMX  1024

// RNE float->bf16 (finite inputs only)
__device__ __forceinline__ u16 f2b(float f) {
  u32 u = __builtin_bit_cast(u32, f);
  u32 r = (u + 0x7fffu + ((u >> 16) & 1u)) >> 16;
  return (u16)r;
}

__device__ __forceinline__ void gl2lds16(const void* g, void* l) {
  __builtin_amdgcn_global_load_lds((const __attribute__((address_space(1))) void*)g,
                                   (__attribute__((address_space(3))) void*)l,
                                   16, 0, 0);
}

// ---------------- fused RMSNorm + weight transpose/cast (one launch) ----------------
// blocks 0..16383: RMSNorm row; blocks 16384..20479: weight prep (castT2 grid 128x32)
__global__ __launch_bounds__(256) void k_pre(const float* __restrict__ x,
                                             const float* __restrict__ gamma,
                                             u16* __restrict__ xn,
                                             const float* __restrict__ wqkv,
                                             const float* __restrict__ wout,
                                             u16* __restrict__ wqT,
                                             u16* __restrict__ woT,
                                             u16* __restrict__ wvc) {
  __shared__ float tile[32][33];
  int blk = blockIdx.x;
  int t = threadIdx.x;
  if (blk < 16384) {
    int row = blk;
    const float4* xr = (const float4*)(x + (size_t)row * DIMX);
    float4 v = xr[t];
    float ss = v.x * v.x + v.y * v.y + v.z * v.z + v.w * v.w;
#pragma unroll
    for (int o = 32; o > 0; o >>= 1) ss += __shfl_xor(ss, o, 64);
    float* wss = &tile[0][0];
    int w = t >> 6;
    if ((t & 63) == 0) wss[w] = ss;
    __syncthreads();
    float tot = wss[0] + wss[1] + wss[2] + wss[3];
    float scale = 32.0f / fmaxf(sqrtf(tot), 1e-12f);
    float4 g = ((const float4*)gamma)[t];
    ushort4 o4;
    o4.x = f2b(v.x * scale * g.x);
    o4.y = f2b(v.y * scale * g.y);
    o4.z = f2b(v.z * scale * g.z);
    o4.w = f2b(v.w * scale * g.w);
    ((ushort4*)xn)[(size_t)row * 256 + t] = o4;
  } else {
    int bb = blk - 16384;            // 0..4095
    int bx = bb & 127, by = bb >> 7; // (128, 32)
    int r0 = by * 32;
    int tx = t & 31, ty = t >> 5;
    if (bx < 96) {
      const float* in; u16* out; int Cc; int c0;
      if (bx < 64) { in = wqkv; out = wqT; Cc = 3072; c0 = bx * 32; }
      else         { in = wout; out = woT; Cc = 1024; c0 = (bx - 64) * 32; }
#pragma unroll
      for (int i = 0; i < 4; i++)
        tile[ty + i * 8][tx] = in[(size_t)(r0 + ty + i * 8) * Cc + c0 + tx];
      __syncthreads();
#pragma unroll
      for (int i = 0; i < 4; i++)
        out[(size_t)(c0 + ty + i * 8) * 1024 + r0 + tx] = f2b(tile[tx][ty + i * 8]);
    } else {
      int c0 = (bx - 96) * 32;
#pragma unroll
      for (int i = 0; i < 4; i++) {
        int r = r0 + ty + i * 8;
        wvc[(size_t)r * 1024 + c0 + tx] = f2b(wqkv[(size_t)r * 3072 + 2048 + c0 + tx]);
      }
    }
  }
}

// ---------------- xn (b: 4096 x 1024) -> xnT (b: 1024 x 4096) bf16 ----------------
__global__ __launch_bounds__(256) void k_xT(const u16* __restrict__ xn,
                                            u16* __restrict__ xnT) {
  __shared__ u16 tile[64][65];
  int bz = blockIdx.z;
  int n0 = blockIdx.x * 64, c0 = blockIdx.y * 64;
  int tx = threadIdx.x, ty = threadIdx.y;   // (64,4)
  const u16* in = xn + (size_t)bz * 4096 * 1024;
  u16* out = xnT + (size_t)bz * 1024 * 4096;
#pragma unroll
  for (int i = 0; i < 16; i++)
    tile[ty + i * 4][tx] = in[(size_t)(n0 + ty + i * 4) * 1024 + c0 + tx];
  __syncthreads();
#pragma unroll
  for (int i = 0; i < 16; i++)
    out[(size_t)(c0 + ty + i * 4) * 4096 + n0 + tx] = tile[tx][ty + i * 4];
}

// ---------------- 256x128 8-wave GEMM core, BK=32, dbuf, swizzled (R8, verified) ----
template<bool SWAP>
__device__ __forceinline__ f32x4 mf(bf16x8 a, bf16x8 b, f32x4 c) {
  return SWAP ? __builtin_amdgcn_mfma_f32_16x16x32_bf16(b, a, c, 0, 0, 0)
              : __builtin_amdgcn_mfma_f32_16x16x32_bf16(a, b, c, 0, 0, 0);
}

__device__ __forceinline__ void stage_ab(const u16* __restrict__ Ag,
                                         const u16* __restrict__ Bg,
                                         u16* dstA, u16* dstB, int t, int k0,
                                         int ldA, int ldB) {
#pragma unroll
  for (int r = 0; r < 2; r++) {
    int c = r * 512 + t;
    int row = c >> 2, s = c & 3;
    int g = s ^ ((row >> 1) & 3);                // inverse swizzle on source
    gl2lds16(Ag + (size_t)row * ldA + k0 + g * 8,
             dstA + (r * 512 + (t >> 6) * 64) * 8);   // wave-uniform base
  }
  {
    int row = t >> 2, s = t & 3;
    int g = s ^ ((row >> 1) & 3);
    gl2lds16(Bg + (size_t)row * ldB + k0 + g * 8,
             dstB + ((t >> 6) * 64) * 8);
  }
}

template<bool SWAP>
__device__ __forceinline__ void gemm_core(const u16* __restrict__ Ag,
                                          const u16* __restrict__ Bg,
                                          u16* lds, int t, f32x4 (&acc)[4][4],
                                          int ldA, int ldB, int nsteps) {
  const int lane = t & 63;
  const int r16 = lane & 15, q = lane >> 4;
  const int wr = (t >> 6) >> 1, wc = (t >> 6) & 1;
  const int arow = wr * 64 + r16;
  const int brow = wc * 64 + r16;

  stage_ab(Ag, Bg, lds, lds + 8192, t, 0, ldA, ldB);
  asm volatile("s_waitcnt vmcnt(0)" ::: "memory");
  __builtin_amdgcn_s_barrier();

  bf16x8 af[4], bf[4];
#pragma unroll 1
  for (int tt = 0; tt < nsteps; tt++) {
    const int cur = (tt & 1) ? 12288 : 0;
    const int nxt = cur ^ 12288;
    int k1 = (tt + 1 == nsteps) ? 0 : (tt + 1) * 32;  // wrap: harmless re-stage
    stage_ab(Ag, Bg, lds + nxt, lds + nxt + 8192, t, k1, ldA, ldB);
    const u16* A = lds + cur;
    const u16* B = lds + cur + 8192;
#pragma unroll
    for (int i = 0; i < 4; i++) {
      int ar = i * 16 + arow;
      int br = i * 16 + brow;
      af[i] = *(const bf16x8*)(A + ar * 32 + (q ^ ((ar >> 1) & 3)) * 8);
      bf[i] = *(const bf16x8*)(B + br * 32 + (q ^ ((br >> 1) & 3)) * 8);
    }
    __builtin_amdgcn_s_setprio(1);
#pragma unroll
    for (int i = 0; i < 4; i++)
#pragma unroll
      for (int j = 0; j < 4; j++)
        acc[i][j] = mf<SWAP>(af[i], bf[j], acc[i][j]);
    __builtin_amdgcn_s_setprio(0);
    asm volatile("s_waitcnt vmcnt(0)" ::: "memory");
    __builtin_amdgcn_s_barrier();
  }
}

// ---------------- G partials, XCD-resident working sets ----------------
// xcd = l&7 pins b = xcd&3, s in {2*(xcd>>2), +1} -> per-XCD slice = 4 MB = L2.
__global__ __launch_bounds__(512, 4) void k_G(const u16* __restrict__ xnT,
                                              float* __restrict__ Gp) {
  __shared__ u16 lds[2 * 12288];
  int l = blockIdx.x;                  // 512
  int xcd = l & 7;
  int b = xcd & 3;
  int s = ((xcd >> 2) << 1) | ((l >> 3) & 1);
  int tile = l >> 4;                   // 0..31
  int mt = tile >> 3, nt = tile & 7;
  int m0 = mt * 256, n0 = nt * 128;
  const u16* base = xnT + (size_t)b * 4194304 + s * 1024;
  int t = threadIdx.x, lane = t & 63;
  int r16 = lane & 15, q = lane >> 4;
  int wr = (t >> 6) >> 1, wc = (t >> 6) & 1;
  f32x4 acc[4][4] = {};
  gemm_core<true>(base + (size_t)m0 * 4096, base + (size_t)n0 * 4096,
                  lds, t, acc, 4096, 4096, 32);
  float* C = Gp + (size_t)(s * 4 + b) * 1048576;
#pragma unroll
  for (int i = 0; i < 4; i++) {
    int m = m0 + wr * 64 + i * 16 + r16;
#pragma unroll
    for (int j = 0; j < 4; j++) {
      int cc = n0 + wc * 64 + j * 16 + q * 4;
      *(f32x4*)(C + (size_t)m * 1024 + cc) = acc[i][j];
    }
  }
}

// ---------------- G = sum_s Gp (bf16) ----------------
__global__ __launch_bounds__(256) void k_Gred(const float* __restrict__ Gp,
                                              u16* __restrict__ G) {
  size_t i = ((size_t)blockIdx.x * 256 + threadIdx.x) * 4;   // over 4M f32
  f32x4 v = {};
#pragma unroll
  for (int s = 0; s < 4; s++)
    v += *(const f32x4*)(Gp + (size_t)s * 4194304 + i);
  ushort4 o4;
  o4.x = f2b(v.x); o4.y = f2b(v.y); o4.z = f2b(v.z); o4.w = f2b(v.w);
  *(ushort4*)(G + i) = o4;
}

// ---------------- V = [WqT; WkT] (2048x1024) x G_b (symmetric) ----------------
__global__ __launch_bounds__(512, 4) void k_V(const u16* __restrict__ wqT,
                                              const u16* __restrict__ G,
                                              u16* __restrict__ V) {
  __shared__ u16 lds[2 * 12288];
  int l = blockIdx.x;
  int b = l & 3;
  int tile = l >> 2;                   // 0..63
  int mt = tile >> 3, nt = tile & 7;   // m: 2048/256, n: 1024/128
  int m0 = mt * 256, n0 = nt * 128;
  int t = threadIdx.x, lane = t & 63;
  int r16 = lane & 15, q = lane >> 4;
  int wr = (t >> 6) >> 1, wc = (t >> 6) & 1;
  f32x4 acc[4][4] = {};
  gemm_core<true>(wqT + (size_t)m0 * 1024,
                  G + (size_t)b * 1048576 + (size_t)n0 * 1024,
                  lds, t, acc, 1024, 1024, 32);
  u16* out = V + (size_t)b * 2097152;
#pragma unroll
  for (int i = 0; i < 4; i++) {
    int m = m0 + wr * 64 + i * 16 + r16;
#pragma unroll
    for (int j = 0; j < 4; j++) {
      int cc = n0 + wc * 64 + j * 16 + q * 4;
      f32x4 a = acc[i][j];
      ushort4 o4;
      o4.x = f2b(a.x); o4.y = f2b(a.y); o4.z = f2b(a.z); o4.w = f2b(a.w);
      *(ushort4*)(out + (size_t)m * 1024 + cc) = o4;
    }
  }
}

// ---------------- fused S + norms + softmax -> PT[bh][e][d] bf16 ----------------
__global__ __launch_bounds__(256) void k_Ssm(const u16* __restrict__ V,
                                             const u16* __restrict__ wqT,
                                             const float* __restrict__ temp,
                                             u16* __restrict__ PT) {
  __shared__ float Sl[64][65];       // pad 65: d-indexed column reads conflict-free
  __shared__ float np[2][128];
  __shared__ float rnk[64];
  __shared__ float redm[4][64];
  __shared__ float reds[4][64];
  int bh = blockIdx.x;
  int b = bh >> 4, h = bh & 15;
  int t = threadIdx.x, lane = t & 63, w = t >> 6;
  int r16 = lane & 15, q = lane >> 4;
  const u16* Vb = V + (size_t)b * 2097152;
  const u16* v2 = Vb + (size_t)(h * 64) * 1024;            // q-part rows
  const u16* wk = wqT + (size_t)(1024 + h * 64) * 1024;    // k rows
  int drow = w * 16 + r16;
  f32x4 acc[4] = {};
#pragma unroll 4
  for (int kk = 0; kk < 1024; kk += 32) {
    bf16x8 aq = *(const bf16x8*)(v2 + (size_t)drow * 1024 + kk + q * 8);
#pragma unroll
    for (int j = 0; j < 4; j++) {
      bf16x8 bk = *(const bf16x8*)(wk + (size_t)(j * 16 + r16) * 1024 + kk + q * 8);
      acc[j] = __builtin_amdgcn_mfma_f32_16x16x32_bf16(bk, aq, acc[j], 0, 0, 0);
    }
  }
  // acc[j]: d = drow (col), e = j*16 + q*4 + reg (row)  [verified mapping]
#pragma unroll
  for (int j = 0; j < 4; j++) {
    int e = j * 16 + q * 4;
    Sl[drow][e + 0] = acc[j].x;
    Sl[drow][e + 1] = acc[j].y;
    Sl[drow][e + 2] = acc[j].z;
    Sl[drow][e + 3] = acc[j].w;
  }
  // norms, 2-way split over k: nq2[d] = V[hd]·wqT[hd], nk2[e] = V[1024+he]·wqT[1024+he]
  {
    int rr = t & 127, half = t >> 7;
    int row = (rr < 64) ? (h * 64 + rr) : (1024 + h * 64 + (rr - 64));
    const u16* vr = Vb + (size_t)row * 1024 + half * 512;
    const u16* wr2 = wqT + (size_t)row * 1024 + half * 512;
    float s = 0.f;
#pragma unroll 4
    for (int c = 0; c < 512; c += 8) {
      bf16x8 a = *(const bf16x8*)(vr + c);
      bf16x8 bb = *(const bf16x8*)(wr2 + c);
#pragma unroll
      for (int k = 0; k < 8; k++) s += (float)a[k] * (float)bb[k];
    }
    np[half][rr] = s;
  }
  __syncthreads();
  if (t < 64) rnk[t] = 1.0f / fmaxf(sqrtf(np[0][64 + t] + np[1][64 + t]), 1e-12f);
  __syncthreads();
  int d = t & 63;
  int e0 = w * 16;
  float nq = sqrtf(np[0][d] + np[1][d]);
  float qs = 8.0f * __expf(temp[h]) / fmaxf(nq, 1e-12f);
  float vals[16];
  float mx = -3.0e38f;
#pragma unroll
  for (int e = 0; e < 16; e++) {
    float v = Sl[d][e0 + e] * qs * rnk[e0 + e];
    vals[e] = v;
    mx = fmaxf(mx, v);
  }
  redm[w][d] = mx;
  __syncthreads();
  float M = fmaxf(fmaxf(redm[0][d], redm[1][d]), fmaxf(redm[2][d], redm[3][d]));
  float ssum = 0.f;
#pragma unroll
  for (int e = 0; e < 16; e++) {
    float v = __expf(vals[e] - M);
    vals[e] = v;
    ssum += v;
  }
  reds[w][d] = ssum;
  __syncthreads();
  float inv = 1.0f / (reds[0][d] + reds[1][d] + reds[2][d] + reds[3][d]);
#pragma unroll
  for (int e = 0; e < 16; e++)
    PT[((size_t)bh * 64 + e0 + e) * 64 + d] = f2b(vals[e] * inv);
}

// ---------------- MT_b[o][h*64+e] = sum_d woT[o][h*64+d] * PT[e][d] ----------------
__global__ __launch_bounds__(256) void k_m(const u16* __restrict__ woT,
                                           const u16* __restrict__ PT,
                                           u16* __restrict__ MT) {
  int bh = blockIdx.x;
  int b = bh >> 4, h = bh & 15;
  int o0 = blockIdx.y * 128;
  int t = threadIdx.x, lane = t & 63, w = t >> 6;
  int r16 = lane & 15, q = lane >> 4;
  const u16* pbase = PT + (size_t)bh * 4096;
  f32x4 acc[2][4] = {};
#pragma unroll
  for (int ks = 0; ks < 2; ks++) {
    int kk = ks * 32 + q * 8;
    bf16x8 af[2], bfr[4];
#pragma unroll
    for (int i = 0; i < 2; i++)
      af[i] = *(const bf16x8*)(woT + (size_t)(o0 + w * 32 + i * 16 + r16) * 1024 + h * 64 + kk);
#pragma unroll
    for (int j = 0; j < 4; j++)
      bfr[j] = *(const bf16x8*)(pbase + (size_t)(j * 16 + r16) * 64 + kk);
#pragma unroll
    for (int i = 0; i < 2; i++)
#pragma unroll
      for (int j = 0; j < 4; j++)
        acc[i][j] = __builtin_amdgcn_mfma_f32_16x16x32_bf16(af[i], bfr[j], acc[i][j], 0, 0, 0);
  }
  u16* dst = MT + (size_t)b * 1024 * 1024;
#pragma unroll
  for (int i = 0; i < 2; i++) {
    int o = o0 + w * 32 + i * 16 + q * 4;
#pragma unroll
    for (int j = 0; j < 4; j++) {
      int e = h * 64 + j * 16 + r16;
      f32x4 a = acc[i][j];
      dst[(size_t)(o + 0) * 1024 + e] = f2b(a.x);
      dst[(size_t)(o + 1) * 1024 + e] = f2b(a.y);
      dst[(size_t)(o + 2) * 1024 + e] = f2b(a.z);
      dst[(size_t)(o + 3) * 1024 + e] = f2b(a.w);
    }
  }
}

// ---------------- Mt_b[o][c] = sum_k wvc[c][k] * MT_b[o][k]  (M transposed) --------
__global__ __launch_bounds__(512, 4) void k_M2(const u16* __restrict__ wvc,
                                               const u16* __restrict__ MT,
                                               u16* __restrict__ Mt) {
  __shared__ u16 lds[2 * 12288];
  int l = blockIdx.x;
  int b = l & 3;
  int tile = l >> 2;                   // 0..31
  int mt = tile >> 3, nt = tile & 7;   // m: c-tiles 1024/256, n: o-tiles 1024/128
  int m0 = mt * 256, n0 = nt * 128;
  int t = threadIdx.x, lane = t & 63;
  int r16 = lane & 15, q = lane >> 4;
  int wr = (t >> 6) >> 1, wc = (t >> 6) & 1;
  f32x4 acc[4][4] = {};
  gemm_core<false>(wvc + (size_t)m0 * 1024,
                   MT + (size_t)b * 1048576 + (size_t)n0 * 1024,
                   lds, t, acc, 1024, 1024, 32);
  u16* out = Mt + (size_t)b * 1048576;
#pragma unroll
  for (int j = 0; j < 4; j++) {
    int cc = n0 + wc * 64 + j * 16 + r16;         // o (B-row)
#pragma unroll
    for (int i = 0; i < 4; i++) {
      int m = m0 + wr * 64 + i * 16 + q * 4;      // c (A-row, reg dim)
      f32x4 a = acc[i][j];
      ushort4 o4;
      o4.x = f2b(a.x); o4.y = f2b(a.y); o4.z = f2b(a.z); o4.w = f2b(a.w);
      *(ushort4*)(out + (size_t)cc * 1024 + m) = o4;
    }
  }
}

// ---------------- final: out = xn (16384x1024) x Mt_b^T (fp32) ----------------
__global__ __launch_bounds__(512, 4) void k_final(const u16* __restrict__ xn,
                                                  const u16* __restrict__ Mt,
                                                  float* __restrict__ C) {
  __shared__ u16 lds[2 * 12288];
  int l = blockIdx.x;
  int xcd = l & 7, c = l >> 3;        // c in [0,64)
  int mt = xcd * 8 + (c & 7);         // 0..63
  int nt = c >> 3;                    // 0..7
  int m0 = mt * 256, n0 = nt * 128;
  int b = m0 >> 12;
  int t = threadIdx.x, lane = t & 63;
  int r16 = lane & 15, q = lane >> 4;
  int wr = (t >> 6) >> 1, wc = (t >> 6) & 1;
  f32x4 acc[4][4] = {};
  gemm_core<true>(xn + (size_t)m0 * 1024,
                  Mt + (size_t)b * 1048576 + (size_t)n0 * 1024,
                  lds, t, acc, 1024, 1024, 32);
#pragma unroll
  for (int i = 0; i < 4; i++) {
    int m = m0 + wr * 64 + i * 16 + r16;
#pragma unroll
    for (int j = 0; j < 4; j++) {
      int cc = n0 + wc * 64 + j * 16 + q * 4;
      *(f32x4*)(C + (size_t)m * 1024 + cc) = acc[i][j];
    }
  }
}

extern "C" void kernel_launch(void* const* d_in, const int* in_sizes, int n_in,
                              void* d_out, int out_size, void* d_ws, size_t ws_size,
                              hipStream_t stream) {
  const float* x     = (const float*)d_in[0];
  const float* gamma = (const float*)d_in[1];
  const float* wqkv  = (const float*)d_in[2];
  const float* temp  = (const float*)d_in[3];
  const float* wout  = (const float*)d_in[4];
  float* out = (float*)d_out;

  char* ws = (char*)d_ws;
  u16* xn    = (u16*)(ws);                       // 33,554,432
  u16* xnT   = (u16*)(ws + 33554432);            // 33,554,432
  u16* wqT   = (u16*)(ws + 67108864);            //  4,194,304 (2048x1024)
  u16* woT   = (u16*)(ws + 71303168);            //  2,097,152
  u16* wvc   = (u16*)(ws + 73400320);            //  2,097,152
  u16* G     = (u16*)(ws + 75497472);            //  8,388,608
  char* R    = ws + 83918848;                    // 67,108,864 region, reused:
  float* Gp  = (float*)R;                        //   64 MB (dead after k_Gred)
  u16* V     = (u16*)R;                          //   16,777,216
  u16* PT    = (u16*)(R + 17825792);             //      524,288
  u16* MT    = (u16*)(R + 18350080);             //    8,388,608
  u16* Mt    = (u16*)(R + 26738688);             //    8,388,608

  k_pre<<<16384 + 4096, 256, 0, stream>>>(x, gamma, xn, wqkv, wout, wqT, woT, wvc);
  k_xT<<<dim3(64, 16, 4), dim3(64, 4), 0, stream>>>(xn, xnT);
  k_G<<<512, 512, 0, stream>>>(xnT, Gp);
  k_Gred<<<4096, 256, 0, stream>>>(Gp, G);
  k_V<<<256, 512, 0, stream>>>(wqT, G, V);
  k_Ssm<<<64, 256, 0, stream>>>(V, wqT, temp, PT);
  k_m<<<dim3(64, 8), 256, 0, stream>>>(woT, PT, MT);
  k_M2<<<128, 512, 0, stream>>>(wvc, MT, Mt);
  k_final<<<512, 512, 0, stream>>>(xn, Mt, out);
}

// Round 11
// 331.451 us; speedup vs baseline: 1.0349x; 1.0003x over previous
//
#include <hip/hip_runtime.h>
#include <stdint.h>

typedef unsigned short u16;
typedef unsigned int u32;
typedef __attribute__((ext_vector_type(8))) __bf16 bf16x8;
typedef __attribute__((ext_vector_type(4))) float f32x4;

#define M_TOT 16384   // B*N tokens
#define DIMX  1024

// RNE float->bf16 (finite inputs only)
__device__ __forceinline__ u16 f2b(float f) {
  u32 u = __builtin_bit_cast(u32, f);
  u32 r = (u + 0x7fffu + ((u >> 16) & 1u)) >> 16;
  return (u16)r;
}

__device__ __forceinline__ void gl2lds16(const void* g, void* l) {
  __builtin_amdgcn_global_load_lds((const __attribute__((address_space(1))) void*)g,
                                   (__attribute__((address_space(3))) void*)l,
                                   16, 0, 0);
}

// ---------------- fused RMSNorm + weight transpose/cast (one launch) ----------------
// blocks 0..16383: RMSNorm row; blocks 16384..20479: weight prep
//   (bx<96: wqT = wqkv^T (3072x1024 -> 3072 rows); bx in [96,128): woT = wout^T)
__global__ __launch_bounds__(256) void k_pre(const float* __restrict__ x,
                                             const float* __restrict__ gamma,
                                             u16* __restrict__ xn,
                                             const float* __restrict__ wqkv,
                                             const float* __restrict__ wout,
                                             u16* __restrict__ wqT,
                                             u16* __restrict__ woT) {
  __shared__ float tile[32][33];
  int blk = blockIdx.x;
  int t = threadIdx.x;
  if (blk < 16384) {
    int row = blk;
    const float4* xr = (const float4*)(x + (size_t)row * DIMX);
    float4 v = xr[t];
    float ss = v.x * v.x + v.y * v.y + v.z * v.z + v.w * v.w;
#pragma unroll
    for (int o = 32; o > 0; o >>= 1) ss += __shfl_xor(ss, o, 64);
    float* wss = &tile[0][0];
    int w = t >> 6;
    if ((t & 63) == 0) wss[w] = ss;
    __syncthreads();
    float tot = wss[0] + wss[1] + wss[2] + wss[3];
    float scale = 32.0f / fmaxf(sqrtf(tot), 1e-12f);
    float4 g = ((const float4*)gamma)[t];
    ushort4 o4;
    o4.x = f2b(v.x * scale * g.x);
    o4.y = f2b(v.y * scale * g.y);
    o4.z = f2b(v.z * scale * g.z);
    o4.w = f2b(v.w * scale * g.w);
    ((ushort4*)xn)[(size_t)row * 256 + t] = o4;
  } else {
    int bb = blk - 16384;            // 0..4095
    int bx = bb & 127, by = bb >> 7; // (128, 32)
    int r0 = by * 32;
    int tx = t & 31, ty = t >> 5;
    const float* in; u16* out; int Cc; int c0;
    if (bx < 96) { in = wqkv; out = wqT; Cc = 3072; c0 = bx * 32; }
    else         { in = wout; out = woT; Cc = 1024; c0 = (bx - 96) * 32; }
#pragma unroll
    for (int i = 0; i < 4; i++)
      tile[ty + i * 8][tx] = in[(size_t)(r0 + ty + i * 8) * Cc + c0 + tx];
    __syncthreads();
#pragma unroll
    for (int i = 0; i < 4; i++)
      out[(size_t)(c0 + ty + i * 8) * 1024 + r0 + tx] = f2b(tile[tx][ty + i * 8]);
  }
}

// ======== GEMM core A: 256x128, 8 waves, BK=32, dbuf, swizzled (R8, 121.9 µs) ======
template<bool SWAP>
__device__ __forceinline__ f32x4 mf(bf16x8 a, bf16x8 b, f32x4 c) {
  return SWAP ? __builtin_amdgcn_mfma_f32_16x16x32_bf16(b, a, c, 0, 0, 0)
              : __builtin_amdgcn_mfma_f32_16x16x32_bf16(a, b, c, 0, 0, 0);
}

// stage A 256x32 (2 chunks/thr) + B 128x32 (1 chunk/thr); swizzled source
__device__ __forceinline__ void stage_ab(const u16* __restrict__ Ag,
                                         const u16* __restrict__ Bg,
                                         u16* dstA, u16* dstB, int t, int k0) {
#pragma unroll
  for (int r = 0; r < 2; r++) {
    int c = r * 512 + t;
    int row = c >> 2, s = c & 3;
    int g = s ^ ((row >> 1) & 3);                // inverse swizzle on source
    gl2lds16(Ag + (size_t)row * 1024 + k0 + g * 8,
             dstA + (r * 512 + (t >> 6) * 64) * 8);   // wave-uniform base
  }
  {
    int row = t >> 2, s = t & 3;
    int g = s ^ ((row >> 1) & 3);
    gl2lds16(Bg + (size_t)row * 1024 + k0 + g * 8,
             dstB + ((t >> 6) * 64) * 8);
  }
}

template<bool SWAP>
__device__ __forceinline__ void gemm_core(const u16* __restrict__ Ag,
                                          const u16* __restrict__ Bg,
                                          u16* lds, int t, f32x4 (&acc)[4][4]) {
  const int lane = t & 63;
  const int r16 = lane & 15, q = lane >> 4;
  const int wr = (t >> 6) >> 1, wc = (t >> 6) & 1;
  const int arow = wr * 64 + r16;
  const int brow = wc * 64 + r16;

  stage_ab(Ag, Bg, lds, lds + 8192, t, 0);
  asm volatile("s_waitcnt vmcnt(0)" ::: "memory");
  __builtin_amdgcn_s_barrier();

  bf16x8 af[4], bf[4];
#pragma unroll 1
  for (int tt = 0; tt < 32; tt++) {
    const int cur = (tt & 1) ? 12288 : 0;
    const int nxt = cur ^ 12288;
    const int k1 = ((tt + 1) & 31) << 5;  // next K (wraps: harmless re-stage)
    stage_ab(Ag, Bg, lds + nxt, lds + nxt + 8192, t, k1);
    const u16* A = lds + cur;
    const u16* B = lds + cur + 8192;
#pragma unroll
    for (int i = 0; i < 4; i++) {
      int ar = i * 16 + arow;
      int br = i * 16 + brow;
      af[i] = *(const bf16x8*)(A + ar * 32 + (q ^ ((ar >> 1) & 3)) * 8);
      bf[i] = *(const bf16x8*)(B + br * 32 + (q ^ ((br >> 1) & 3)) * 8);
    }
    __builtin_amdgcn_s_setprio(1);
#pragma unroll
    for (int i = 0; i < 4; i++)
#pragma unroll
      for (int j = 0; j < 4; j++)
        acc[i][j] = mf<SWAP>(af[i], bf[j], acc[i][j]);
    __builtin_amdgcn_s_setprio(0);
    asm volatile("s_waitcnt vmcnt(0)" ::: "memory");
    __builtin_amdgcn_s_barrier();
  }
}

// ======== GEMM core B: 128x128, 4 waves, BK=64, dbuf, swizzled (R4, best-total) =====
// stage one 128x64 tile (16 KiB): 4 x gl2lds16 per thread (256 thr)
__device__ __forceinline__ void stage128(const u16* __restrict__ g,
                                         u16* dst, int t, int k0) {
#pragma unroll
  for (int r = 0; r < 4; r++) {
    int c = r * 256 + t;
    int row = c >> 3;
    int sl = (c & 7) ^ (row & 7);                // inverse swizzle on source
    gl2lds16(g + (size_t)row * 1024 + k0 + sl * 8,
             dst + (r * 256 + (t >> 6) * 64) * 8);  // linear, wave-uniform base
  }
}

template<bool SWAP>
__device__ __forceinline__ void gemm_core128(const u16* __restrict__ Ag,
                                             const u16* __restrict__ Bg,
                                             u16* lds, int t, f32x4 (&acc)[4][4]) {
  const int lane = t & 63;
  const int r16 = lane & 15, q = lane >> 4;
  const int s0 = (q ^ (r16 & 7)) * 8;   // u16 off of 8-elem slot, kq=0; kq=1: ^32
  const int wr = (t >> 6) >> 1, wc = (t >> 6) & 1;
  const int arow = wr * 64 + r16;
  const int brow = wc * 64 + r16;

  stage128(Ag, lds + 0,    t, 0);
  stage128(Bg, lds + 8192, t, 0);
  asm volatile("s_waitcnt vmcnt(0)" ::: "memory");
  __builtin_amdgcn_s_barrier();

  bf16x8 af[4][2], bf[4][2];
#pragma unroll 1
  for (int tt = 0; tt < 16; tt++) {
    const int bo = (tt & 1) << 14;        // buffer u16 offset 0/16384
    const int nb = bo ^ 16384;
    const int k1 = ((tt + 1) & 15) << 6;  // next K-tile (wraps: harmless re-stage)
    stage128(Ag, lds + nb,        t, k1);
    stage128(Bg, lds + nb + 8192, t, k1);
    const u16* A = lds + bo;
    const u16* B = lds + bo + 8192;
#pragma unroll
    for (int i = 0; i < 4; i++) {
      af[i][0] = *(const bf16x8*)(A + (i * 16 + arow) * 64 + s0);
      af[i][1] = *(const bf16x8*)(A + (i * 16 + arow) * 64 + (s0 ^ 32));
      bf[i][0] = *(const bf16x8*)(B + (i * 16 + brow) * 64 + s0);
      bf[i][1] = *(const bf16x8*)(B + (i * 16 + brow) * 64 + (s0 ^ 32));
    }
    __builtin_amdgcn_s_setprio(1);
#pragma unroll
    for (int kq = 0; kq < 2; kq++)
#pragma unroll
      for (int i = 0; i < 4; i++)
#pragma unroll
        for (int j = 0; j < 4; j++)
          acc[i][j] = mf<SWAP>(af[i][kq], bf[j][kq], acc[i][j]);
    __builtin_amdgcn_s_setprio(0);
    asm volatile("s_waitcnt vmcnt(0)" ::: "memory");   // next tile landed
    __builtin_amdgcn_s_barrier();
  }
}

// ---------------- GEMM1 merged q/k/v (256x128 tiles, 512 thr) — R8 verbatim -------
__global__ __launch_bounds__(512, 4) void k_gemm1(const u16* __restrict__ A,
                                                  const u16* __restrict__ Bt,   // 3072x1024
                                                  u16* __restrict__ qkT,        // 2048x16384
                                                  u16* __restrict__ vmat,       // 16384x1024
                                                  float* __restrict__ sumsq) {  // [4][2048]
  __shared__ u16 lds[2 * 12288];   // 48 KiB
  int l = blockIdx.x;
  int xcd = l & 7, c = l >> 3;        // c in [0,192)
  int mt = xcd * 8 + (c & 7);         // 0..63
  int nt = c >> 3;                    // 0..23
  int m0 = mt * 256, n0 = nt * 128;
  int t = threadIdx.x, lane = t & 63;
  int r16 = lane & 15, q = lane >> 4;
  int wr = (t >> 6) >> 1, wc = (t >> 6) & 1;
  f32x4 acc[4][4] = {};
  if (n0 < 2048) {
    gemm_core<false>(A + (size_t)m0 * 1024, Bt + (size_t)n0 * 1024, lds, t, acc);
    int b = m0 >> 12;
#pragma unroll
    for (int j = 0; j < 4; j++) {
      int cc = n0 + wc * 64 + j * 16 + r16;
      float colss = 0.f;
#pragma unroll
      for (int i = 0; i < 4; i++) {
        f32x4 a = acc[i][j];
        colss += a.x * a.x + a.y * a.y + a.z * a.z + a.w * a.w;
        int m = m0 + wr * 64 + i * 16 + q * 4;
        ushort4 o4;
        o4.x = f2b(a.x); o4.y = f2b(a.y); o4.z = f2b(a.z); o4.w = f2b(a.w);
        *(ushort4*)(qkT + (size_t)cc * M_TOT + m) = o4;
      }
      colss += __shfl_xor(colss, 16, 64);
      colss += __shfl_xor(colss, 32, 64);
      if (lane < 16) atomicAdd(&sumsq[b * 2048 + cc], colss);
    }
  } else {
    gemm_core<true>(A + (size_t)m0 * 1024, Bt + (size_t)n0 * 1024, lds, t, acc);
    int vc0 = n0 - 2048;
#pragma unroll
    for (int i = 0; i < 4; i++) {
      int m = m0 + wr * 64 + i * 16 + r16;
#pragma unroll
      for (int j = 0; j < 4; j++) {
        int cc = vc0 + wc * 64 + j * 16 + q * 4;
        f32x4 a = acc[i][j];
        ushort4 o4;
        o4.x = f2b(a.x); o4.y = f2b(a.y); o4.z = f2b(a.z); o4.w = f2b(a.w);
        *(ushort4*)(vmat + (size_t)m * 1024 + cc) = o4;
      }
    }
  }
}

// ---------------- S partials, LDS-coalesced (R4 verbatim) ----------------
__global__ __launch_bounds__(256) void k_attn_s(const u16* __restrict__ qkT,
                                                float* __restrict__ Spart) {
  __shared__ u16 Ql[64 * 256];   // 32 KiB
  __shared__ u16 Kl[64 * 256];   // 32 KiB
  int bh = blockIdx.x, split = blockIdx.y;
  int b = bh >> 4, h = bh & 15;
  int t = threadIdx.x, lane = t & 63, w = t >> 6;
  int r16 = lane & 15, q = lane >> 4;
  const u16* qbase = qkT + (size_t)(h * 64) * M_TOT + b * 4096 + split * 1024;
  const u16* kbase = qkT + (size_t)(1024 + h * 64) * M_TOT + b * 4096 + split * 1024;
  int drow = w * 16 + r16;                 // this lane's q-row (d)
  f32x4 acc[4] = {};
#pragma unroll 1
  for (int it = 0; it < 4; it++) {
    int ncol = it * 256;
#pragma unroll
    for (int r = 0; r < 8; r++) {
      int ch = r * 256 + t;
      int row = ch >> 5;
      int sl = (ch & 31) ^ (row & 31);     // inverse swizzle on source
      gl2lds16(qbase + (size_t)row * M_TOT + ncol + sl * 8,
               Ql + (r * 256 + w * 64) * 8);
      gl2lds16(kbase + (size_t)row * M_TOT + ncol + sl * 8,
               Kl + (r * 256 + w * 64) * 8);
    }
    asm volatile("s_waitcnt vmcnt(0)" ::: "memory");
    __syncthreads();
#pragma unroll
    for (int it2 = 0; it2 < 8; it2++) {
      bf16x8 aq = *(const bf16x8*)(Ql + drow * 256 + (((it2 * 4 + q) ^ (drow & 31)) * 8));
#pragma unroll
      for (int j = 0; j < 4; j++) {
        int erow = j * 16 + r16;
        bf16x8 bk = *(const bf16x8*)(Kl + erow * 256 + (((it2 * 4 + q) ^ (erow & 31)) * 8));
        acc[j] = __builtin_amdgcn_mfma_f32_16x16x32_bf16(bk, aq, acc[j], 0, 0, 0);
      }
    }
    __syncthreads();
  }
  float* Sp = Spart + ((size_t)split * 64 + bh) * 4096;
#pragma unroll
  for (int j = 0; j < 4; j++)
    *(f32x4*)(Sp + drow * 64 + j * 16 + q * 4) = acc[j];
}

// ---------------- sum 4 partials + scale + softmax -> PT[bh][e][d] bf16 ----------------
__global__ __launch_bounds__(256) void k_softmax(const float* __restrict__ Spart,
                                                 const float* __restrict__ sumsq,
                                                 const float* __restrict__ temp,
                                                 u16* __restrict__ PT) {
  int bh = blockIdx.x;
  int b = bh >> 4, h = bh & 15;
  int t = threadIdx.x;
  int d = t & 63, w = t >> 6;
  int e0 = w * 16;
  __shared__ float rnk[64];
  __shared__ float redm[4][64];
  __shared__ float reds[4][64];
  if (t < 64) rnk[t] = 1.0f / fmaxf(sqrtf(sumsq[b * 2048 + 1024 + h * 64 + t]), 1e-12f);
  __syncthreads();
  float nq = sqrtf(sumsq[b * 2048 + h * 64 + d]);
  float qs = 8.0f * __expf(temp[h]) / fmaxf(nq, 1e-12f);
  const float* Sp = Spart + (size_t)bh * 4096 + d * 64 + e0;
  float vals[16];
#pragma unroll
  for (int e = 0; e < 16; e += 4) {
    f32x4 v = {};
#pragma unroll
    for (int s = 0; s < 4; s++)
      v += *(const f32x4*)(Sp + (size_t)s * 64 * 4096 + e);
    vals[e + 0] = v.x; vals[e + 1] = v.y; vals[e + 2] = v.z; vals[e + 3] = v.w;
  }
  float mx = -3.0e38f;
#pragma unroll
  for (int e = 0; e < 16; e++) {
    float v = vals[e] * qs * rnk[e0 + e];
    vals[e] = v;
    mx = fmaxf(mx, v);
  }
  redm[w][d] = mx;
  __syncthreads();
  float M = fmaxf(fmaxf(redm[0][d], redm[1][d]), fmaxf(redm[2][d], redm[3][d]));
  float s = 0.f;
#pragma unroll
  for (int e = 0; e < 16; e++) {
    float v = __expf(vals[e] - M);
    vals[e] = v;
    s += v;
  }
  reds[w][d] = s;
  __syncthreads();
  float inv = 1.0f / (reds[0][d] + reds[1][d] + reds[2][d] + reds[3][d]);
#pragma unroll
  for (int e = 0; e < 16; e++)
    PT[((size_t)bh * 64 + e0 + e) * 64 + d] = f2b(vals[e] * inv);
}

// ---------------- MT_b[o][h*64+e] = sum_d woT[o][h*64+d] * PT[e][d] ----------------
__global__ __launch_bounds__(256) void k_m(const u16* __restrict__ woT,
                                           const u16* __restrict__ PT,
                                           u16* __restrict__ MT) {
  int bh = blockIdx.x;
  int b = bh >> 4, h = bh & 15;
  int o0 = blockIdx.y * 128;
  int t = threadIdx.x, lane = t & 63, w = t >> 6;
  int r16 = lane & 15, q = lane >> 4;
  const u16* pbase = PT + (size_t)bh * 4096;
  f32x4 acc[2][4] = {};
#pragma unroll
  for (int ks = 0; ks < 2; ks++) {
    int kk = ks * 32 + q * 8;
    bf16x8 af[2], bfr[4];
#pragma unroll
    for (int i = 0; i < 2; i++)
      af[i] = *(const bf16x8*)(woT + (size_t)(o0 + w * 32 + i * 16 + r16) * 1024 + h * 64 + kk);
#pragma unroll
    for (int j = 0; j < 4; j++)
      bfr[j] = *(const bf16x8*)(pbase + (size_t)(j * 16 + r16) * 64 + kk);
#pragma unroll
    for (int i = 0; i < 2; i++)
#pragma unroll
      for (int j = 0; j < 4; j++)
        acc[i][j] = __builtin_amdgcn_mfma_f32_16x16x32_bf16(af[i], bfr[j], acc[i][j], 0, 0, 0);
  }
  u16* dst = MT + (size_t)b * 1024 * 1024;
#pragma unroll
  for (int i = 0; i < 2; i++) {
    int o = o0 + w * 32 + i * 16 + q * 4;
#pragma unroll
    for (int j = 0; j < 4; j++) {
      int e = h * 64 + j * 16 + r16;
      f32x4 a = acc[i][j];
      dst[(size_t)(o + 0) * 1024 + e] = f2b(a.x);
      dst[(size_t)(o + 1) * 1024 + e] = f2b(a.y);
      dst[(size_t)(o + 2) * 1024 + e] = f2b(a.z);
      dst[(size_t)(o + 3) * 1024 + e] = f2b(a.w);
    }
  }
}

// ---------------- GEMM2: out = vmat @ MT_b^T (fp32 out), R4 verbatim ----------------
__global__ __launch_bounds__(256, 2) void k_gemm2(const u16* __restrict__ A,
                                                  const u16* __restrict__ Bt,
                                                  float* __restrict__ C) {
  __shared__ u16 lds[2 * 16384];   // 64 KiB
  int l = blockIdx.x;
  int xcd = l & 7, c = l >> 3;        // c in [0,128)
  int mt = xcd * 16 + (c & 15);       // 0..127
  int nt = c >> 4;                    // 0..7
  int m0 = mt * 128, n0 = nt * 128;
  int b = m0 >> 12;
  const u16* Bb = Bt + (size_t)b * 1024 * 1024;
  int t = threadIdx.x, lane = t & 63;
  int r16 = lane & 15, q = lane >> 4;
  int wr = (t >> 6) >> 1, wc = (t >> 6) & 1;
  f32x4 acc[4][4] = {};
  gemm_core128<true>(A + (size_t)m0 * 1024, Bb + (size_t)n0 * 1024, lds, t, acc);
#pragma unroll
  for (int i = 0; i < 4; i++) {
    int m = m0 + wr * 64 + i * 16 + r16;
#pragma unroll
    for (int j = 0; j < 4; j++) {
      int cc = n0 + wc * 64 + j * 16 + q * 4;
      *(f32x4*)(C + (size_t)m * 1024 + cc) = acc[i][j];
    }
  }
}

extern "C" void kernel_launch(void* const* d_in, const int* in_sizes, int n_in,
                              void* d_out, int out_size, void* d_ws, size_t ws_size,
                              hipStream_t stream) {
  const float* x     = (const float*)d_in[0];
  const float* gamma = (const float*)d_in[1];
  const float* wqkv  = (const float*)d_in[2];
  const float* temp  = (const float*)d_in[3];
  const float* wout  = (const float*)d_in[4];
  float* out = (float*)d_out;

  char* ws = (char*)d_ws;
  size_t off = 0;
  u16* xn = (u16*)(ws + off);    off += (size_t)M_TOT * 1024 * 2;   // 32M (dead after gemm1)
  u16* wqT = (u16*)(ws + off);   off += (size_t)3072 * 1024 * 2;
  u16* woT = (u16*)(ws + off);   off += (size_t)1024 * 1024 * 2;
  u16* qkT = (u16*)(ws + off);   off += (size_t)2048 * M_TOT * 2;
  u16* vmat = (u16*)(ws + off);  off += (size_t)M_TOT * 1024 * 2;
  float* sumsq = (float*)(ws + off); off += (size_t)4 * 2048 * 4;
  u16* PT = (u16*)(ws + off);    off += (size_t)64 * 64 * 64 * 2;
  u16* MT = (u16*)(ws + off);    off += (size_t)4 * 1024 * 1024 * 2;

  // Spart[4][64][64][64] fp32 (4 MB) aliases xn (32 MB), dead after gemm1.
  float* Spart = (float*)xn;

  // only sumsq is atomic-accumulated
  hipMemsetAsync((void*)sumsq, 0, (size_t)4 * 2048 * 4, stream);

  k_pre<<<16384 + 4096, 256, 0, stream>>>(x, gamma, xn, wqkv, wout, wqT, woT);
  k_gemm1<<<1536, 512, 0, stream>>>(xn, wqT, qkT, vmat, sumsq);
  k_attn_s<<<dim3(64, 4), 256, 0, stream>>>(qkT, Spart);
  k_softmax<<<64, 256, 0, stream>>>(Spart, sumsq, temp, PT);
  k_m<<<dim3(64, 8), 256, 0, stream>>>(woT, PT, MT);
  k_gemm2<<<1024, 256, 0, stream>>>(vmat, MT, out);
}